// Round 11
// baseline (749.518 us; speedup 1.0000x reference)
//
#include <hip/hip_runtime.h>
#include <hip/hip_bf16.h>

// Problem constants (fixed by the harness)
#define NN  50000      // nodes
#define EE  800000     // edges before self-loops
#define NE2 850000     // edges + self-loops
#define NB  512        // graphs
#define NRT 3125       // row tiles of 16 (NN = 3125*16 exactly)
#define NSB 196        // scan blocks = ceil(NN/256)
// GAT1: F=128 -> 4 heads x 64 (256). GAT2: 256 -> 1 head x 128. GCN: 128 -> 64.

#define BN_RS 0.9999950000374997f   // 1/sqrt(1+1e-5)

typedef __attribute__((ext_vector_type(8))) short short8;
typedef __attribute__((ext_vector_type(4))) float f32x4;

__device__ __forceinline__ float bf2f(__hip_bfloat16 v) { return __bfloat162float(v); }
__device__ __forceinline__ unsigned short f2b(float v) {
    __hip_bfloat16 b = __float2bfloat16(v);
    return *reinterpret_cast<unsigned short*>(&b);
}
__device__ __forceinline__ float u2f(unsigned short u) {
    union { unsigned u; float f; } c; c.u = ((unsigned)u) << 16; return c.f;
}
__device__ __forceinline__ float4 u42f4(ushort4 v) {
    float4 r; r.x = u2f(v.x); r.y = u2f(v.y); r.z = u2f(v.z); r.w = u2f(v.w); return r;
}
__device__ __forceinline__ float lrelu01(float v) { return v > 0.f ? v : 0.01f * v; }
__device__ __forceinline__ float lrelu02(float v) { return v > 0.f ? v : 0.2f * v; }

__device__ __forceinline__ void edge_sd(const int* __restrict__ ei, int e, int& s, int& d) {
    if (e < EE) { s = ei[e]; d = ei[EE + e]; }
    else        { s = e - EE; d = e - EE; }      // self-loop
}

__device__ __forceinline__ float ldf(const void* p, int i, bool bf) {
    return bf ? bf2f(((const __hip_bfloat16*)p)[i]) : ((const float*)p)[i];
}

#define NSEG 20
#define WTOT 85578
#define XQUADS (NN * 32)
// prep index space: x quads | weights | W1t | W2t | Wgt | edge-degree counting
#define PREP_TOT (XQUADS + WTOT + 32768 + 32768 + 8192 + NE2)
struct SegArgs { const void* src[NSEG]; int off[NSEG]; };

// fused: per-block dtype detect + x->bf16 + fp32 weights + B^T transposes + degree count
__global__ __launch_bounds__(256) void prep_k(SegArgs a,
                                              const void* __restrict__ x_raw,
                                              ushort4* __restrict__ xb4,
                                              const void* __restrict__ W1r,
                                              const void* __restrict__ W2r,
                                              const void* __restrict__ Wgr,
                                              float* __restrict__ wf,
                                              unsigned short* __restrict__ W1t,
                                              unsigned short* __restrict__ W2t,
                                              unsigned short* __restrict__ Wgt,
                                              const int* __restrict__ ei,
                                              int* __restrict__ degi,
                                              int* __restrict__ flag) {
    __shared__ int cnt;
    int t = threadIdx.x;
    if (t == 0) cnt = 0;
    __syncthreads();
    {
        int c = 0;
        const unsigned* xw = (const unsigned*)x_raw;
#pragma unroll
        for (int k = 0; k < 4; ++k) {
            unsigned w = xw[t * 4 + k];
            unsigned ef = (w >> 7) & 0xFFu;
            if (ef >= 100u && ef <= 140u) c++;
        }
        atomicAdd(&cnt, c);
    }
    __syncthreads();
    bool bf = (cnt > 512);
    if (blockIdx.x == 0 && t == 0) *flag = bf ? 1 : 0;

    int i = blockIdx.x * 256 + t;
    if (i >= PREP_TOT) return;
    if (i < XQUADS) {
        ushort4 o;
        if (bf) o = ((const ushort4*)x_raw)[i];
        else {
            float4 v = ((const float4*)x_raw)[i];
            o.x = f2b(v.x); o.y = f2b(v.y); o.z = f2b(v.z); o.w = f2b(v.w);
        }
        xb4[i] = o;
        return;
    }
    i -= XQUADS;
    if (i < WTOT) {
        int s = 0;
#pragma unroll
        for (int k = 1; k < NSEG; ++k) if (i >= a.off[k]) s = k;
        wf[i] = ldf(a.src[s], i - a.off[s], bf);
        return;
    }
    i -= WTOT;
    if (i < 32768) {           // W1 [128][256] -> W1t[n*128+k]
        int n = i >> 7, k = i & 127;
        W1t[i] = f2b(ldf(W1r, k * 256 + n, bf));
        return;
    }
    i -= 32768;
    if (i < 32768) {           // W2 [256][128] -> W2t[n*256+k]
        int n = i >> 8, k = i & 255;
        W2t[i] = f2b(ldf(W2r, k * 128 + n, bf));
        return;
    }
    i -= 32768;
    if (i < 8192) {            // Wg [128][64] -> Wgt[n*128+k]
        int n = i >> 7, k = i & 127;
        Wgt[i] = f2b(ldf(Wgr, k * 64 + n, bf));
        return;
    }
    i -= 8192;
    {                          // degree count (degi pre-zeroed by memset)
        int s, d; edge_sd(ei, i, s, d);
        atomicAdd(&degi[d], 1);
    }
}

// ---------------- CSR scan phases ----------------
__global__ __launch_bounds__(256) void pscan_k(const int* __restrict__ degi,
                                               int* __restrict__ incl, int* __restrict__ bsum) {
    __shared__ int tmp[256];
    int t = threadIdx.x;
    int i = blockIdx.x * 256 + t;
    int v = (i < NN) ? degi[i] : 0;
    tmp[t] = v;
    __syncthreads();
#pragma unroll
    for (int off = 1; off < 256; off <<= 1) {
        int u = (t >= off) ? tmp[t - off] : 0;
        __syncthreads();
        tmp[t] += u;
        __syncthreads();
    }
    if (i < NN) incl[i] = tmp[t];
    if (t == 255) bsum[blockIdx.x] = tmp[255];
}

__global__ __launch_bounds__(256) void bscan_k(int* __restrict__ bsum) {
    __shared__ int tmp[256];
    int t = threadIdx.x;
    tmp[t] = (t < NSB) ? bsum[t] : 0;
    __syncthreads();
#pragma unroll
    for (int off = 1; off < 256; off <<= 1) {
        int u = (t >= off) ? tmp[t - off] : 0;
        __syncthreads();
        tmp[t] += u;
        __syncthreads();
    }
    if (t < NSB) bsum[t] = tmp[t];
}

// phase 3: exclusive row_ptr + cursor + dis + graph bounds
__global__ __launch_bounds__(256) void fscan_k(const int* __restrict__ degi,
                                               const int* __restrict__ incl,
                                               const int* __restrict__ bsum,
                                               const int* __restrict__ batch,
                                               int* __restrict__ row_ptr, int* __restrict__ cursor,
                                               float* __restrict__ dis, int* __restrict__ gstart) {
    int i = blockIdx.x * 256 + threadIdx.x;
    if (i <= NB) {
        int lo = 0, hi = NN;
        while (lo < hi) { int mid = (lo + hi) >> 1; if (batch[mid] < i) lo = mid + 1; else hi = mid; }
        gstart[i] = lo;
    }
    if (i >= NN) return;
    int dg = degi[i];
    int base = (blockIdx.x > 0) ? bsum[blockIdx.x - 1] : 0;
    int ex = base + incl[i] - dg;
    row_ptr[i] = ex; cursor[i] = ex;
    dis[i] = dg > 0 ? rsqrtf((float)dg) : 0.f;
    if (i == NN - 1) row_ptr[NN] = bsum[NSB - 1];
}

__global__ __launch_bounds__(256) void scatter_k(const int* __restrict__ ei,
                                                 int* __restrict__ cursor,
                                                 int* __restrict__ csr_src) {
    int e = blockIdx.x * 256 + threadIdx.x;
    if (e >= NE2) return;
    int s, d; edge_sd(ei, e, s, d);
    int pos = atomicAdd(&cursor[d], 1);
    csr_src[pos] = s;
}

// ---------------- GEMM1 + fused GAT1 scores ----------------
__global__ __launch_bounds__(256) void mgemm1_k(const short* __restrict__ A,    // xb [N][128]
                                                const short* __restrict__ Bt,   // W1t [256][128]
                                                unsigned short* __restrict__ C, // h1b [N][256]
                                                const float* __restrict__ a_s,  // [256]
                                                const float* __restrict__ a_d,
                                                float* __restrict__ sc_s,       // [N*4]
                                                float* __restrict__ sc_d) {
    int wave = threadIdx.x >> 6, lane = threadIdx.x & 63;
    int rt = blockIdx.x, cg = wave;
    int l15 = lane & 15, quad = lane >> 4;
    const short* ap = A + (size_t)(rt * 16 + l15) * 128 + quad * 8;
    const short* bp = Bt + (size_t)(cg * 64 + l15) * 128 + quad * 8;
    f32x4 acc[4] = {};
    for (int k0 = 0; k0 < 128; k0 += 32) {
        short8 a = *(const short8*)(ap + k0);
#pragma unroll
        for (int j = 0; j < 4; ++j) {
            short8 b = *(const short8*)(bp + (size_t)j * 16 * 128 + k0);
            acc[j] = __builtin_amdgcn_mfma_f32_16x16x32_bf16(a, b, acc[j], 0, 0, 0);
        }
    }
    float asv[4], adv[4];
#pragma unroll
    for (int j = 0; j < 4; ++j) {
        asv[j] = a_s[cg * 64 + j * 16 + l15];
        adv[j] = a_d[cg * 64 + j * 16 + l15];
    }
    float ss[4] = {0.f, 0.f, 0.f, 0.f}, sd[4] = {0.f, 0.f, 0.f, 0.f};
#pragma unroll
    for (int j = 0; j < 4; ++j) {
        int n = cg * 64 + j * 16 + l15;
#pragma unroll
        for (int r = 0; r < 4; ++r) {
            float v = acc[j][r];
            C[(size_t)(rt * 16 + quad * 4 + r) * 256 + n] = f2b(v);
            ss[r] = fmaf(v, asv[j], ss[r]);
            sd[r] = fmaf(v, adv[j], sd[r]);
        }
    }
#pragma unroll
    for (int off = 1; off < 16; off <<= 1) {
#pragma unroll
        for (int r = 0; r < 4; ++r) {
            ss[r] += __shfl_xor(ss[r], off);
            sd[r] += __shfl_xor(sd[r], off);
        }
    }
    if (l15 == 0) {
#pragma unroll
        for (int r = 0; r < 4; ++r) {
            int node = rt * 16 + quad * 4 + r;
            sc_s[node * 4 + cg] = ss[r];
            sc_d[node * 4 + cg] = sd[r];
        }
    }
}

// ---------------- GEMM2 + fused GAT2 scores ----------------
__global__ __launch_bounds__(256) void mgemm2_k(const short* __restrict__ A,    // x1b [N][256]
                                                const short* __restrict__ Bt,   // W2t [128][256]
                                                unsigned short* __restrict__ C, // h2b [N][128]
                                                const float* __restrict__ a_s,  // [128]
                                                const float* __restrict__ a_d,
                                                float* __restrict__ sc_s,       // [N]
                                                float* __restrict__ sc_d) {
    __shared__ float sred[4][16][2];
    int wave = threadIdx.x >> 6, lane = threadIdx.x & 63;
    int gidx = blockIdx.x * 4 + wave;
    bool act = gidx < NRT * 2;
    int gcl = act ? gidx : NRT * 2 - 1;
    int rt = gcl >> 1, cg = gcl & 1;
    int l15 = lane & 15, quad = lane >> 4;
    const short* ap = A + (size_t)(rt * 16 + l15) * 256 + quad * 8;
    const short* bp = Bt + (size_t)(cg * 64 + l15) * 256 + quad * 8;
    f32x4 acc[4] = {};
    for (int k0 = 0; k0 < 256; k0 += 32) {
        short8 a = *(const short8*)(ap + k0);
#pragma unroll
        for (int j = 0; j < 4; ++j) {
            short8 b = *(const short8*)(bp + (size_t)j * 16 * 256 + k0);
            acc[j] = __builtin_amdgcn_mfma_f32_16x16x32_bf16(a, b, acc[j], 0, 0, 0);
        }
    }
    float asv[4], adv[4];
#pragma unroll
    for (int j = 0; j < 4; ++j) {
        asv[j] = a_s[cg * 64 + j * 16 + l15];
        adv[j] = a_d[cg * 64 + j * 16 + l15];
    }
    float ss[4] = {0.f, 0.f, 0.f, 0.f}, sd[4] = {0.f, 0.f, 0.f, 0.f};
#pragma unroll
    for (int j = 0; j < 4; ++j) {
        int n = cg * 64 + j * 16 + l15;
#pragma unroll
        for (int r = 0; r < 4; ++r) {
            float v = acc[j][r];
            if (act) C[(size_t)(rt * 16 + quad * 4 + r) * 128 + n] = f2b(v);
            ss[r] = fmaf(v, asv[j], ss[r]);
            sd[r] = fmaf(v, adv[j], sd[r]);
        }
    }
#pragma unroll
    for (int off = 1; off < 16; off <<= 1) {
#pragma unroll
        for (int r = 0; r < 4; ++r) {
            ss[r] += __shfl_xor(ss[r], off);
            sd[r] += __shfl_xor(sd[r], off);
        }
    }
    if (l15 == 0) {
#pragma unroll
        for (int r = 0; r < 4; ++r) {
            sred[wave][quad * 4 + r][0] = ss[r];
            sred[wave][quad * 4 + r][1] = sd[r];
        }
    }
    __syncthreads();
    if (threadIdx.x < 32) {
        int rl = threadIdx.x >> 4, row = threadIdx.x & 15;
        int g2 = blockIdx.x * 4 + rl * 2;
        if (g2 < NRT * 2) {
            int node = (g2 >> 1) * 16 + row;
            sc_s[node] = sred[rl * 2][row][0] + sred[rl * 2 + 1][row][0];
            sc_d[node] = sred[rl * 2][row][1] + sred[rl * 2 + 1][row][1];
        }
    }
}

// ---------------- GEMM3 (plain): hg = x2 @ Wg ----------------
__global__ __launch_bounds__(256) void mgemm3_k(const short* __restrict__ A,    // x2b [N][128]
                                                const short* __restrict__ Bt,   // Wgt [64][128]
                                                unsigned short* __restrict__ C) {
    int wave = threadIdx.x >> 6, lane = threadIdx.x & 63;
    int gidx = blockIdx.x * 4 + wave;
    if (gidx >= NRT) return;
    int rt = gidx;
    int l15 = lane & 15, quad = lane >> 4;
    const short* ap = A + (size_t)(rt * 16 + l15) * 128 + quad * 8;
    const short* bp = Bt + (size_t)l15 * 128 + quad * 8;
    f32x4 acc[4] = {};
    for (int k0 = 0; k0 < 128; k0 += 32) {
        short8 a = *(const short8*)(ap + k0);
#pragma unroll
        for (int j = 0; j < 4; ++j) {
            short8 b = *(const short8*)(bp + (size_t)j * 16 * 128 + k0);
            acc[j] = __builtin_amdgcn_mfma_f32_16x16x32_bf16(a, b, acc[j], 0, 0, 0);
        }
    }
#pragma unroll
    for (int j = 0; j < 4; ++j) {
        int n = j * 16 + l15;
#pragma unroll
        for (int r = 0; r < 4; ++r)
            C[(size_t)(rt * 16 + quad * 4 + r) * 64 + n] = f2b(acc[j][r]);
    }
}

__device__ __forceinline__ float sel4(float4 v, int head) {
    float ab = (head & 1) ? v.y : v.x;
    float cd = (head & 1) ? v.w : v.z;
    return (head & 2) ? cd : ab;
}

// ---------------- GAT1 aggregate: wave/node, scalar CSR+score loads, 8-deep pipeline ------
__global__ __launch_bounds__(256) void agg1_k(const int* __restrict__ row_ptr,
                                              const int* __restrict__ csr_src,
                                              const ushort4* __restrict__ h1b,  // [N*64]
                                              const float4* __restrict__ sc_s4, // [N]
                                              const float4* __restrict__ sc_d4, // [N]
                                              const float4* __restrict__ b1,    // [64]
                                              const float4* __restrict__ g1,
                                              const float4* __restrict__ bb1,
                                              ushort4* __restrict__ x1b) {
    int n = __builtin_amdgcn_readfirstlane((blockIdx.x * 256 + threadIdx.x) >> 6);
    int lane = threadIdx.x & 63;
    if (n >= NN) return;
    int row = row_ptr[n], end = row_ptr[n + 1];
    int head = lane >> 4;
    float scd_h = sel4(sc_d4[n], head);
    float4 acc = {0.f, 0.f, 0.f, 0.f};
    float den = 0.f;
    int c = row;
    for (; c + 7 < end; c += 8) {
        int s[8];
#pragma unroll
        for (int j = 0; j < 8; ++j) s[j] = csr_src[c + j];
        float4 scs[8];
#pragma unroll
        for (int j = 0; j < 8; ++j) scs[j] = sc_s4[s[j]];
        ushort4 hu[8];
#pragma unroll
        for (int j = 0; j < 8; ++j) hu[j] = h1b[(size_t)s[j] * 64 + lane];
        float e[8];
#pragma unroll
        for (int j = 0; j < 8; ++j) { e[j] = __expf(lrelu02(sel4(scs[j], head) + scd_h)); den += e[j]; }
#pragma unroll
        for (int j = 0; j < 8; ++j) {
            float4 hv = u42f4(hu[j]);
            acc.x = fmaf(hv.x, e[j], acc.x);
            acc.y = fmaf(hv.y, e[j], acc.y);
            acc.z = fmaf(hv.z, e[j], acc.z);
            acc.w = fmaf(hv.w, e[j], acc.w);
        }
    }
    for (; c < end; ++c) {
        int s0 = csr_src[c];
        float4 scs0 = sc_s4[s0];
        float4 hv0 = u42f4(h1b[(size_t)s0 * 64 + lane]);
        float e0 = __expf(lrelu02(sel4(scs0, head) + scd_h));
        den += e0;
        acc.x = fmaf(hv0.x, e0, acc.x);
        acc.y = fmaf(hv0.y, e0, acc.y);
        acc.z = fmaf(hv0.z, e0, acc.z);
        acc.w = fmaf(hv0.w, e0, acc.w);
    }
    float inv = 1.f / (den + 1e-16f);
    float4 bb = b1[lane], gg = g1[lane], be = bb1[lane];
    ushort4 o;
    o.x = f2b(lrelu01(acc.x * inv + bb.x) * (gg.x * BN_RS) + be.x);
    o.y = f2b(lrelu01(acc.y * inv + bb.y) * (gg.y * BN_RS) + be.y);
    o.z = f2b(lrelu01(acc.z * inv + bb.z) * (gg.z * BN_RS) + be.z);
    o.w = f2b(lrelu01(acc.w * inv + bb.w) * (gg.w * BN_RS) + be.w);
    x1b[(size_t)n * 64 + lane] = o;
}

// ---------------- GAT2 aggregate: wave-uniform c, scalar CSR/score loads, 2 groups --------
__global__ __launch_bounds__(256) void agg2_k(const int* __restrict__ row_ptr,
                                              const int* __restrict__ csr_src,
                                              const ushort4* __restrict__ h2b,  // [N*32]
                                              const float* __restrict__ sc_s,   // [N]
                                              const float* __restrict__ sc_d,
                                              const float4* __restrict__ b2,    // [32]
                                              const float4* __restrict__ g2,
                                              const float4* __restrict__ bb2,
                                              ushort4* __restrict__ x2b) {
    int n = __builtin_amdgcn_readfirstlane((blockIdx.x * 256 + threadIdx.x) >> 6);
    int lane = threadIdx.x & 63;
    if (n >= NN) return;
    int g = lane >> 5, sl = lane & 31;
    int row = row_ptr[n], end = row_ptr[n + 1];
    float scd = sc_d[n];
    float4 acc = {0.f, 0.f, 0.f, 0.f};
    float den = 0.f;
    int c = row;
    for (; c + 7 < end; c += 8) {
        int s[8];
#pragma unroll
        for (int j = 0; j < 8; ++j) s[j] = csr_src[c + j];
        float sc[8];
#pragma unroll
        for (int j = 0; j < 8; ++j) sc[j] = sc_s[s[j]];
        ushort4 hu[4];
#pragma unroll
        for (int k = 0; k < 4; ++k) {
            int sg = g ? s[2 * k + 1] : s[2 * k];
            hu[k] = h2b[(size_t)sg * 32 + sl];
        }
#pragma unroll
        for (int k = 0; k < 4; ++k) {
            float scg = g ? sc[2 * k + 1] : sc[2 * k];
            float e = __expf(lrelu02(scg + scd));
            den += e;
            float4 hv = u42f4(hu[k]);
            acc.x = fmaf(hv.x, e, acc.x);
            acc.y = fmaf(hv.y, e, acc.y);
            acc.z = fmaf(hv.z, e, acc.z);
            acc.w = fmaf(hv.w, e, acc.w);
        }
    }
    for (int cc = c + g; cc < end; cc += 2) {
        int s0 = csr_src[cc];
        float e = __expf(lrelu02(sc_s[s0] + scd));
        den += e;
        float4 hv = u42f4(h2b[(size_t)s0 * 32 + sl]);
        acc.x = fmaf(hv.x, e, acc.x);
        acc.y = fmaf(hv.y, e, acc.y);
        acc.z = fmaf(hv.z, e, acc.z);
        acc.w = fmaf(hv.w, e, acc.w);
    }
    den += __shfl_xor(den, 32);
    acc.x += __shfl_xor(acc.x, 32);
    acc.y += __shfl_xor(acc.y, 32);
    acc.z += __shfl_xor(acc.z, 32);
    acc.w += __shfl_xor(acc.w, 32);
    if (g == 0) {
        float inv = 1.f / (den + 1e-16f);
        float4 bb = b2[sl], gg = g2[sl], be = bb2[sl];
        ushort4 o;
        o.x = f2b(lrelu01(acc.x * inv + bb.x) * (gg.x * BN_RS) + be.x);
        o.y = f2b(lrelu01(acc.y * inv + bb.y) * (gg.y * BN_RS) + be.y);
        o.z = f2b(lrelu01(acc.z * inv + bb.z) * (gg.z * BN_RS) + be.z);
        o.w = f2b(lrelu01(acc.w * inv + bb.w) * (gg.w * BN_RS) + be.w);
        x2b[(size_t)n * 32 + sl] = o;
    }
}

// ---------------- GCN aggregate: wave-uniform c, scalar CSR/dis loads, 4 groups ----------
__global__ __launch_bounds__(256) void gcn_k(const int* __restrict__ row_ptr,
                                             const int* __restrict__ csr_src,
                                             const ushort4* __restrict__ hgb,  // [N*16]
                                             const float* __restrict__ dis,
                                             const float4* __restrict__ bg,    // [16]
                                             float4* __restrict__ x3) {        // [N*16]
    int n = __builtin_amdgcn_readfirstlane((blockIdx.x * 256 + threadIdx.x) >> 6);
    int lane = threadIdx.x & 63;
    if (n >= NN) return;
    int g = lane >> 4, sl = lane & 15;
    int row = row_ptr[n], end = row_ptr[n + 1];
    float dn = dis[n];
    float4 acc = {0.f, 0.f, 0.f, 0.f};
    int c = row;
    for (; c + 15 < end; c += 16) {
        int s[16];
#pragma unroll
        for (int j = 0; j < 16; ++j) s[j] = csr_src[c + j];
        float w[16];
#pragma unroll
        for (int j = 0; j < 16; ++j) w[j] = dis[s[j]];
        ushort4 hu[4];
#pragma unroll
        for (int k = 0; k < 4; ++k) {
            int sg0 = (g & 1) ? s[4 * k + 1] : s[4 * k];
            int sg1 = (g & 1) ? s[4 * k + 3] : s[4 * k + 2];
            int sg = (g & 2) ? sg1 : sg0;
            hu[k] = hgb[(size_t)sg * 16 + sl];
        }
#pragma unroll
        for (int k = 0; k < 4; ++k) {
            float w0 = (g & 1) ? w[4 * k + 1] : w[4 * k];
            float w1 = (g & 1) ? w[4 * k + 3] : w[4 * k + 2];
            float wg = (g & 2) ? w1 : w0;
            float4 hv = u42f4(hu[k]);
            acc.x = fmaf(hv.x, wg, acc.x);
            acc.y = fmaf(hv.y, wg, acc.y);
            acc.z = fmaf(hv.z, wg, acc.z);
            acc.w = fmaf(hv.w, wg, acc.w);
        }
    }
    for (int cc = c + g; cc < end; cc += 4) {
        int s0 = csr_src[cc];
        float w0 = dis[s0];
        float4 hv0 = u42f4(hgb[(size_t)s0 * 16 + sl]);
        acc.x = fmaf(hv0.x, w0, acc.x);
        acc.y = fmaf(hv0.y, w0, acc.y);
        acc.z = fmaf(hv0.z, w0, acc.z);
        acc.w = fmaf(hv0.w, w0, acc.w);
    }
#pragma unroll
    for (int off = 16; off <= 32; off <<= 1) {
        acc.x += __shfl_xor(acc.x, off);
        acc.y += __shfl_xor(acc.y, off);
        acc.z += __shfl_xor(acc.z, off);
        acc.w += __shfl_xor(acc.w, off);
    }
    if (g == 0) {
        float4 bb = bg[sl];
        float4 o;
        o.x = lrelu01(acc.x * dn + bb.x);
        o.y = lrelu01(acc.y * dn + bb.y);
        o.z = lrelu01(acc.z * dn + bb.z);
        o.w = lrelu01(acc.w * dn + bb.w);
        x3[(size_t)n * 16 + sl] = o;
    }
}

// ---------------- fused mean-pool + MLP head: block per graph ----------------
__global__ __launch_bounds__(256) void poolmlp_k(const float* __restrict__ x3,
                                                 const int* __restrict__ gstart,
                                                 const float* __restrict__ l1W,
                                                 const float* __restrict__ l1b,
                                                 const float* __restrict__ g3,
                                                 const float* __restrict__ b3,
                                                 const float* __restrict__ l2W,
                                                 const float* __restrict__ l2b,
                                                 void* __restrict__ outp,
                                                 const int* __restrict__ flag) {
    __shared__ float red[4][64];
    __shared__ float pl[64];
    __shared__ float y1s[128];
    int g = blockIdx.x, t = threadIdx.x;
    int c = t & 63, r = t >> 6;
    int s = gstart[g], e = gstart[g + 1];
    float sum = 0.f;
    for (int n = s + r; n < e; n += 4) sum += x3[(size_t)n * 64 + c];
    red[r][c] = sum;
    __syncthreads();
    if (t < 64) {
        float v = red[0][t] + red[1][t] + red[2][t] + red[3][t];
        int cnt = e - s; if (cnt < 1) cnt = 1;
        pl[t] = v / (float)cnt;
    }
    __syncthreads();
    if (t < 128) {
        float acc = l1b[t];
#pragma unroll 8
        for (int j = 0; j < 64; ++j) acc = fmaf(pl[j], l1W[j * 128 + t], acc);
        acc = acc * (g3[t] * BN_RS) + b3[t];
        y1s[t] = lrelu01(acc);
    }
    __syncthreads();
    if (t < 10) {
        float o = l2b[t];
#pragma unroll 8
        for (int j = 0; j < 128; ++j) o = fmaf(y1s[j], l2W[j * 10 + t], o);
        if (*flag) ((__hip_bfloat16*)outp)[g * 10 + t] = __float2bfloat16(o);
        else       ((float*)outp)[g * 10 + t] = o;
    }
}

// weight segment sizes (W1,as1,ad1,b1,W2,as2,ad2,b2,Wg,bg,bn1g,bn1b,bn2g,bn2b,bn3g,bn3b,l1W,l1b,l2W,l2b)
static const int kSegN[NSEG]  = {32768, 256, 256, 256, 32768, 128, 128, 128, 8192, 64,
                                 256, 256, 128, 128, 128, 128, 8192, 128, 1280, 10};
static const int kSegIn[NSEG] = {3, 4, 5, 6, 7, 8, 9, 10, 11, 12, 13, 14, 15, 16, 17, 18, 19, 20, 21, 22};

extern "C" void kernel_launch(void* const* d_in, const int* in_sizes, int n_in,
                              void* d_out, int out_size, void* d_ws, size_t ws_size,
                              hipStream_t stream) {
    const void* x_raw = d_in[0];
    const int*  ei    = (const int*)d_in[1];
    const int*  batch = (const int*)d_in[2];

    // ---- workspace layout ----
    int*   flag = (int*)d_ws;
    float* ws   = (float*)d_ws;
    unsigned short* xb = (unsigned short*)(ws + 16);          // N*128 bf16
    float* wf   = ws + 16 + (size_t)NN * 64;                  // 85584 fp32 canonical
    unsigned short* W1t = (unsigned short*)(wf + 85584);      // 32768 bf16 [256][128]
    unsigned short* W2t = W1t + 32768;                        // 32768 bf16 [128][256]
    unsigned short* Wgt = W2t + 32768;                        // 8192  bf16 [64][128]
    unsigned short* h1b = Wgt + 8192;                         // N*256 bf16 (reused as h2b)
    unsigned short* x1b = h1b + (size_t)NN * 256;             // N*256 bf16
    unsigned short* x2b = x1b + (size_t)NN * 256;             // N*128 bf16
    unsigned short* hgb = x2b + (size_t)NN * 128;             // N*64 bf16
    float* x3   = (float*)(hgb + (size_t)NN * 64);            // N*64 fp32
    float* sc_s1 = x3 + (size_t)NN * 64;                      // N*4
    float* sc_d1 = sc_s1 + (size_t)NN * 4;                    // N*4
    float* sc_s2 = sc_d1 + (size_t)NN * 4;                    // N
    float* sc_d2 = sc_s2 + NN;                                // N
    float* disb  = sc_d2 + NN;                                // N
    int*   gstart = (int*)(disb + NN);                        // B+1
    int*   degi   = gstart + NB + 4;                          // N
    int*   incl   = degi + NN;                                // N
    int*   bsum   = incl + NN;                                // 256
    int*   row_ptr = bsum + 256;                              // N+1
    int*   cursor  = row_ptr + NN + 1;                        // N
    int*   csr_src = cursor + NN;                             // NE2

    int off[NSEG]; int o = 0;
    for (int s = 0; s < NSEG; ++s) { off[s] = o; o += kSegN[s]; }
    float* as1f = wf + off[1];  float* ad1f = wf + off[2];
    float* b1f  = wf + off[3];  float* as2f = wf + off[5];
    float* ad2f = wf + off[6];  float* b2f  = wf + off[7];
    float* bgf  = wf + off[9];  float* bn1g = wf + off[10]; float* bn1b = wf + off[11];
    float* bn2g = wf + off[12]; float* bn2b = wf + off[13]; float* bn3g = wf + off[14];
    float* bn3b = wf + off[15]; float* l1Wf = wf + off[16]; float* l1bf = wf + off[17];
    float* l2Wf = wf + off[18]; float* l2bf = wf + off[19];

    unsigned short* h2b = h1b;   // h1b dead after agg1_k

    // ---- prep: degi zero (memset) + detect/convert/transpose/degree-count (one kernel) ----
    hipMemsetAsync(degi, 0, NN * sizeof(int), stream);
    SegArgs sa;
    for (int s = 0; s < NSEG; ++s) { sa.src[s] = d_in[kSegIn[s]]; sa.off[s] = off[s]; }
    prep_k<<<(PREP_TOT + 255) / 256, 256, 0, stream>>>(sa, x_raw, (ushort4*)xb,
                                                       d_in[3], d_in[7], d_in[11],
                                                       wf, W1t, W2t, Wgt, ei, degi, flag);

    // ---- CSR build (by destination) + graph bounds ----
    pscan_k<<<NSB, 256, 0, stream>>>(degi, incl, bsum);
    bscan_k<<<1, 256, 0, stream>>>(bsum);
    fscan_k<<<NSB, 256, 0, stream>>>(degi, incl, bsum, batch, row_ptr, cursor, disb, gstart);
    scatter_k<<<(NE2 + 255) / 256, 256, 0, stream>>>(ei, cursor, csr_src);

    // ---- GAT layer 1 (scores fused into GEMM) ----
    mgemm1_k<<<NRT, 256, 0, stream>>>((const short*)xb, (const short*)W1t, h1b,
                                      as1f, ad1f, sc_s1, sc_d1);
    agg1_k<<<12500, 256, 0, stream>>>(row_ptr, csr_src, (const ushort4*)h1b,
                                      (const float4*)sc_s1, (const float4*)sc_d1,
                                      (const float4*)b1f, (const float4*)bn1g,
                                      (const float4*)bn1b, (ushort4*)x1b);

    // ---- GAT layer 2 (scores fused into GEMM) ----
    mgemm2_k<<<(NRT * 2 + 3) / 4, 256, 0, stream>>>((const short*)x1b, (const short*)W2t, h2b,
                                                    as2f, ad2f, sc_s2, sc_d2);
    agg2_k<<<12500, 256, 0, stream>>>(row_ptr, csr_src, (const ushort4*)h2b,
                                      sc_s2, sc_d2,
                                      (const float4*)b2f, (const float4*)bn2g,
                                      (const float4*)bn2b, (ushort4*)x2b);

    // ---- GCN + fused pool/MLP ----
    mgemm3_k<<<(NRT + 3) / 4, 256, 0, stream>>>((const short*)x2b, (const short*)Wgt, hgb);
    gcn_k<<<12500, 256, 0, stream>>>(row_ptr, csr_src, (const ushort4*)hgb, disb,
                                     (const float4*)bgf, (float4*)x3);
    poolmlp_k<<<NB, 256, 0, stream>>>(x3, gstart, l1Wf, l1bf, bn3g, bn3b, l2Wf, l2bf,
                                      d_out, flag);
}

// Round 12
// 448.502 us; speedup vs baseline: 1.6712x; 1.6712x over previous
//
#include <hip/hip_runtime.h>
#include <hip/hip_bf16.h>

// Problem constants (fixed by the harness)
#define NN  50000      // nodes
#define EE  800000     // edges before self-loops
#define NE2 850000     // edges + self-loops
#define NB  512        // graphs
#define NRT 3125       // row tiles of 16 (NN = 3125*16 exactly)
#define NSB 196        // scan blocks = ceil(NN/256)
// GAT1: F=128 -> 4 heads x 64 (256). GAT2: 256 -> 1 head x 128. GCN: 128 -> 64.

#define BN_RS 0.9999950000374997f   // 1/sqrt(1+1e-5)

typedef __attribute__((ext_vector_type(8))) short short8;
typedef __attribute__((ext_vector_type(4))) float f32x4;

__device__ __forceinline__ float bf2f(__hip_bfloat16 v) { return __bfloat162float(v); }
__device__ __forceinline__ unsigned short f2b(float v) {
    __hip_bfloat16 b = __float2bfloat16(v);
    return *reinterpret_cast<unsigned short*>(&b);
}
__device__ __forceinline__ float u2f(unsigned short u) {
    union { unsigned u; float f; } c; c.u = ((unsigned)u) << 16; return c.f;
}
__device__ __forceinline__ float4 u42f4(ushort4 v) {
    float4 r; r.x = u2f(v.x); r.y = u2f(v.y); r.z = u2f(v.z); r.w = u2f(v.w); return r;
}
__device__ __forceinline__ float lrelu01(float v) { return v > 0.f ? v : 0.01f * v; }
__device__ __forceinline__ float lrelu02(float v) { return v > 0.f ? v : 0.2f * v; }

__device__ __forceinline__ void edge_sd(const int* __restrict__ ei, int e, int& s, int& d) {
    if (e < EE) { s = ei[e]; d = ei[EE + e]; }
    else        { s = e - EE; d = e - EE; }      // self-loop
}

__device__ __forceinline__ float ldf(const void* p, int i, bool bf) {
    return bf ? bf2f(((const __hip_bfloat16*)p)[i]) : ((const float*)p)[i];
}

#define NSEG 20
#define WTOT 85578
#define XQUADS (NN * 32)
// prep index space: x quads | weights | W1t | W2t | Wgt | edge-degree counting
#define PREP_TOT (XQUADS + WTOT + 32768 + 32768 + 8192 + NE2)
struct SegArgs { const void* src[NSEG]; int off[NSEG]; };

// fused: per-block dtype detect + x->bf16 + fp32 weights + B^T transposes + degree count
__global__ __launch_bounds__(256) void prep_k(SegArgs a,
                                              const void* __restrict__ x_raw,
                                              ushort4* __restrict__ xb4,
                                              const void* __restrict__ W1r,
                                              const void* __restrict__ W2r,
                                              const void* __restrict__ Wgr,
                                              float* __restrict__ wf,
                                              unsigned short* __restrict__ W1t,
                                              unsigned short* __restrict__ W2t,
                                              unsigned short* __restrict__ Wgt,
                                              const int* __restrict__ ei,
                                              int* __restrict__ degi,
                                              int* __restrict__ flag) {
    __shared__ int cnt;
    int t = threadIdx.x;
    if (t == 0) cnt = 0;
    __syncthreads();
    {
        int c = 0;
        const unsigned* xw = (const unsigned*)x_raw;
#pragma unroll
        for (int k = 0; k < 4; ++k) {
            unsigned w = xw[t * 4 + k];
            unsigned ef = (w >> 7) & 0xFFu;
            if (ef >= 100u && ef <= 140u) c++;
        }
        atomicAdd(&cnt, c);
    }
    __syncthreads();
    bool bf = (cnt > 512);
    if (blockIdx.x == 0 && t == 0) *flag = bf ? 1 : 0;

    int i = blockIdx.x * 256 + t;
    if (i >= PREP_TOT) return;
    if (i < XQUADS) {
        ushort4 o;
        if (bf) o = ((const ushort4*)x_raw)[i];
        else {
            float4 v = ((const float4*)x_raw)[i];
            o.x = f2b(v.x); o.y = f2b(v.y); o.z = f2b(v.z); o.w = f2b(v.w);
        }
        xb4[i] = o;
        return;
    }
    i -= XQUADS;
    if (i < WTOT) {
        int s = 0;
#pragma unroll
        for (int k = 1; k < NSEG; ++k) if (i >= a.off[k]) s = k;
        wf[i] = ldf(a.src[s], i - a.off[s], bf);
        return;
    }
    i -= WTOT;
    if (i < 32768) {           // W1 [128][256] -> W1t[n*128+k]
        int n = i >> 7, k = i & 127;
        W1t[i] = f2b(ldf(W1r, k * 256 + n, bf));
        return;
    }
    i -= 32768;
    if (i < 32768) {           // W2 [256][128] -> W2t[n*256+k]
        int n = i >> 8, k = i & 255;
        W2t[i] = f2b(ldf(W2r, k * 128 + n, bf));
        return;
    }
    i -= 32768;
    if (i < 8192) {            // Wg [128][64] -> Wgt[n*128+k]
        int n = i >> 7, k = i & 127;
        Wgt[i] = f2b(ldf(Wgr, k * 64 + n, bf));
        return;
    }
    i -= 8192;
    {                          // degree count (degi pre-zeroed by memset)
        int s, d; edge_sd(ei, i, s, d);
        atomicAdd(&degi[d], 1);
    }
}

// ---------------- CSR scan phases ----------------
__global__ __launch_bounds__(256) void pscan_k(const int* __restrict__ degi,
                                               int* __restrict__ incl, int* __restrict__ bsum) {
    __shared__ int tmp[256];
    int t = threadIdx.x;
    int i = blockIdx.x * 256 + t;
    int v = (i < NN) ? degi[i] : 0;
    tmp[t] = v;
    __syncthreads();
#pragma unroll
    for (int off = 1; off < 256; off <<= 1) {
        int u = (t >= off) ? tmp[t - off] : 0;
        __syncthreads();
        tmp[t] += u;
        __syncthreads();
    }
    if (i < NN) incl[i] = tmp[t];
    if (t == 255) bsum[blockIdx.x] = tmp[255];
}

__global__ __launch_bounds__(256) void bscan_k(int* __restrict__ bsum) {
    __shared__ int tmp[256];
    int t = threadIdx.x;
    tmp[t] = (t < NSB) ? bsum[t] : 0;
    __syncthreads();
#pragma unroll
    for (int off = 1; off < 256; off <<= 1) {
        int u = (t >= off) ? tmp[t - off] : 0;
        __syncthreads();
        tmp[t] += u;
        __syncthreads();
    }
    if (t < NSB) bsum[t] = tmp[t];
}

// phase 3: exclusive row_ptr + cursor + dis + graph bounds
__global__ __launch_bounds__(256) void fscan_k(const int* __restrict__ degi,
                                               const int* __restrict__ incl,
                                               const int* __restrict__ bsum,
                                               const int* __restrict__ batch,
                                               int* __restrict__ row_ptr, int* __restrict__ cursor,
                                               float* __restrict__ dis, int* __restrict__ gstart) {
    int i = blockIdx.x * 256 + threadIdx.x;
    if (i <= NB) {
        int lo = 0, hi = NN;
        while (lo < hi) { int mid = (lo + hi) >> 1; if (batch[mid] < i) lo = mid + 1; else hi = mid; }
        gstart[i] = lo;
    }
    if (i >= NN) return;
    int dg = degi[i];
    int base = (blockIdx.x > 0) ? bsum[blockIdx.x - 1] : 0;
    int ex = base + incl[i] - dg;
    row_ptr[i] = ex; cursor[i] = ex;
    dis[i] = dg > 0 ? rsqrtf((float)dg) : 0.f;
    if (i == NN - 1) row_ptr[NN] = bsum[NSB - 1];
}

__global__ __launch_bounds__(256) void scatter_k(const int* __restrict__ ei,
                                                 int* __restrict__ cursor,
                                                 int* __restrict__ csr_src) {
    int e = blockIdx.x * 256 + threadIdx.x;
    if (e >= NE2) return;
    int s, d; edge_sd(ei, e, s, d);
    int pos = atomicAdd(&cursor[d], 1);
    csr_src[pos] = s;
}

// ---------------- GEMM1 + fused GAT1 scores ----------------
__global__ __launch_bounds__(256) void mgemm1_k(const short* __restrict__ A,    // xb [N][128]
                                                const short* __restrict__ Bt,   // W1t [256][128]
                                                unsigned short* __restrict__ C, // h1b [N][256]
                                                const float* __restrict__ a_s,  // [256]
                                                const float* __restrict__ a_d,
                                                float* __restrict__ sc_s,       // [N*4]
                                                float* __restrict__ sc_d) {
    int wave = threadIdx.x >> 6, lane = threadIdx.x & 63;
    int rt = blockIdx.x, cg = wave;
    int l15 = lane & 15, quad = lane >> 4;
    const short* ap = A + (size_t)(rt * 16 + l15) * 128 + quad * 8;
    const short* bp = Bt + (size_t)(cg * 64 + l15) * 128 + quad * 8;
    f32x4 acc[4] = {};
    for (int k0 = 0; k0 < 128; k0 += 32) {
        short8 a = *(const short8*)(ap + k0);
#pragma unroll
        for (int j = 0; j < 4; ++j) {
            short8 b = *(const short8*)(bp + (size_t)j * 16 * 128 + k0);
            acc[j] = __builtin_amdgcn_mfma_f32_16x16x32_bf16(a, b, acc[j], 0, 0, 0);
        }
    }
    float asv[4], adv[4];
#pragma unroll
    for (int j = 0; j < 4; ++j) {
        asv[j] = a_s[cg * 64 + j * 16 + l15];
        adv[j] = a_d[cg * 64 + j * 16 + l15];
    }
    float ss[4] = {0.f, 0.f, 0.f, 0.f}, sd[4] = {0.f, 0.f, 0.f, 0.f};
#pragma unroll
    for (int j = 0; j < 4; ++j) {
        int n = cg * 64 + j * 16 + l15;
#pragma unroll
        for (int r = 0; r < 4; ++r) {
            float v = acc[j][r];
            C[(size_t)(rt * 16 + quad * 4 + r) * 256 + n] = f2b(v);
            ss[r] = fmaf(v, asv[j], ss[r]);
            sd[r] = fmaf(v, adv[j], sd[r]);
        }
    }
#pragma unroll
    for (int off = 1; off < 16; off <<= 1) {
#pragma unroll
        for (int r = 0; r < 4; ++r) {
            ss[r] += __shfl_xor(ss[r], off);
            sd[r] += __shfl_xor(sd[r], off);
        }
    }
    if (l15 == 0) {
#pragma unroll
        for (int r = 0; r < 4; ++r) {
            int node = rt * 16 + quad * 4 + r;
            sc_s[node * 4 + cg] = ss[r];
            sc_d[node * 4 + cg] = sd[r];
        }
    }
}

// ---------------- GEMM2 + fused GAT2 scores ----------------
__global__ __launch_bounds__(256) void mgemm2_k(const short* __restrict__ A,    // x1b [N][256]
                                                const short* __restrict__ Bt,   // W2t [128][256]
                                                unsigned short* __restrict__ C, // h2b [N][128]
                                                const float* __restrict__ a_s,  // [128]
                                                const float* __restrict__ a_d,
                                                float* __restrict__ sc_s,       // [N]
                                                float* __restrict__ sc_d) {
    __shared__ float sred[4][16][2];
    int wave = threadIdx.x >> 6, lane = threadIdx.x & 63;
    int gidx = blockIdx.x * 4 + wave;
    bool act = gidx < NRT * 2;
    int gcl = act ? gidx : NRT * 2 - 1;
    int rt = gcl >> 1, cg = gcl & 1;
    int l15 = lane & 15, quad = lane >> 4;
    const short* ap = A + (size_t)(rt * 16 + l15) * 256 + quad * 8;
    const short* bp = Bt + (size_t)(cg * 64 + l15) * 256 + quad * 8;
    f32x4 acc[4] = {};
    for (int k0 = 0; k0 < 256; k0 += 32) {
        short8 a = *(const short8*)(ap + k0);
#pragma unroll
        for (int j = 0; j < 4; ++j) {
            short8 b = *(const short8*)(bp + (size_t)j * 16 * 256 + k0);
            acc[j] = __builtin_amdgcn_mfma_f32_16x16x32_bf16(a, b, acc[j], 0, 0, 0);
        }
    }
    float asv[4], adv[4];
#pragma unroll
    for (int j = 0; j < 4; ++j) {
        asv[j] = a_s[cg * 64 + j * 16 + l15];
        adv[j] = a_d[cg * 64 + j * 16 + l15];
    }
    float ss[4] = {0.f, 0.f, 0.f, 0.f}, sd[4] = {0.f, 0.f, 0.f, 0.f};
#pragma unroll
    for (int j = 0; j < 4; ++j) {
        int n = cg * 64 + j * 16 + l15;
#pragma unroll
        for (int r = 0; r < 4; ++r) {
            float v = acc[j][r];
            if (act) C[(size_t)(rt * 16 + quad * 4 + r) * 128 + n] = f2b(v);
            ss[r] = fmaf(v, asv[j], ss[r]);
            sd[r] = fmaf(v, adv[j], sd[r]);
        }
    }
#pragma unroll
    for (int off = 1; off < 16; off <<= 1) {
#pragma unroll
        for (int r = 0; r < 4; ++r) {
            ss[r] += __shfl_xor(ss[r], off);
            sd[r] += __shfl_xor(sd[r], off);
        }
    }
    if (l15 == 0) {
#pragma unroll
        for (int r = 0; r < 4; ++r) {
            sred[wave][quad * 4 + r][0] = ss[r];
            sred[wave][quad * 4 + r][1] = sd[r];
        }
    }
    __syncthreads();
    if (threadIdx.x < 32) {
        int rl = threadIdx.x >> 4, row = threadIdx.x & 15;
        int g2 = blockIdx.x * 4 + rl * 2;
        if (g2 < NRT * 2) {
            int node = (g2 >> 1) * 16 + row;
            sc_s[node] = sred[rl * 2][row][0] + sred[rl * 2 + 1][row][0];
            sc_d[node] = sred[rl * 2][row][1] + sred[rl * 2 + 1][row][1];
        }
    }
}

// ---------------- GEMM3 (plain): hg = x2 @ Wg ----------------
__global__ __launch_bounds__(256) void mgemm3_k(const short* __restrict__ A,    // x2b [N][128]
                                                const short* __restrict__ Bt,   // Wgt [64][128]
                                                unsigned short* __restrict__ C) {
    int wave = threadIdx.x >> 6, lane = threadIdx.x & 63;
    int gidx = blockIdx.x * 4 + wave;
    if (gidx >= NRT) return;
    int rt = gidx;
    int l15 = lane & 15, quad = lane >> 4;
    const short* ap = A + (size_t)(rt * 16 + l15) * 128 + quad * 8;
    const short* bp = Bt + (size_t)l15 * 128 + quad * 8;
    f32x4 acc[4] = {};
    for (int k0 = 0; k0 < 128; k0 += 32) {
        short8 a = *(const short8*)(ap + k0);
#pragma unroll
        for (int j = 0; j < 4; ++j) {
            short8 b = *(const short8*)(bp + (size_t)j * 16 * 128 + k0);
            acc[j] = __builtin_amdgcn_mfma_f32_16x16x32_bf16(a, b, acc[j], 0, 0, 0);
        }
    }
#pragma unroll
    for (int j = 0; j < 4; ++j) {
        int n = j * 16 + l15;
#pragma unroll
        for (int r = 0; r < 4; ++r)
            C[(size_t)(rt * 16 + quad * 4 + r) * 64 + n] = f2b(acc[j][r]);
    }
}

__device__ __forceinline__ float sel4(float4 v, int head) {
    float ab = (head & 1) ? v.y : v.x;
    float cd = (head & 1) ? v.w : v.z;
    return (head & 2) ? cd : ab;
}

// ---------------- GAT1 aggregate: wave/node, scalar CSR+score loads, 8-deep pipeline ------
__global__ __launch_bounds__(256) void agg1_k(const int* __restrict__ row_ptr,
                                              const int* __restrict__ csr_src,
                                              const ushort4* __restrict__ h1b,  // [N*64]
                                              const float4* __restrict__ sc_s4, // [N]
                                              const float4* __restrict__ sc_d4, // [N]
                                              const float4* __restrict__ b1,    // [64]
                                              const float4* __restrict__ g1,
                                              const float4* __restrict__ bb1,
                                              ushort4* __restrict__ x1b) {
    int n = __builtin_amdgcn_readfirstlane((blockIdx.x * 256 + threadIdx.x) >> 6);
    int lane = threadIdx.x & 63;
    if (n >= NN) return;
    int row = row_ptr[n], end = row_ptr[n + 1];
    int head = lane >> 4;
    float scd_h = sel4(sc_d4[n], head);
    float4 acc = {0.f, 0.f, 0.f, 0.f};
    float den = 0.f;
    int c = row;
    for (; c + 7 < end; c += 8) {
        int s[8];
#pragma unroll
        for (int j = 0; j < 8; ++j) s[j] = csr_src[c + j];
        float4 scs[8];
#pragma unroll
        for (int j = 0; j < 8; ++j) scs[j] = sc_s4[s[j]];
        ushort4 hu[8];
#pragma unroll
        for (int j = 0; j < 8; ++j) hu[j] = h1b[(size_t)s[j] * 64 + lane];
        float e[8];
#pragma unroll
        for (int j = 0; j < 8; ++j) { e[j] = __expf(lrelu02(sel4(scs[j], head) + scd_h)); den += e[j]; }
#pragma unroll
        for (int j = 0; j < 8; ++j) {
            float4 hv = u42f4(hu[j]);
            acc.x = fmaf(hv.x, e[j], acc.x);
            acc.y = fmaf(hv.y, e[j], acc.y);
            acc.z = fmaf(hv.z, e[j], acc.z);
            acc.w = fmaf(hv.w, e[j], acc.w);
        }
    }
    for (; c < end; ++c) {
        int s0 = csr_src[c];
        float4 scs0 = sc_s4[s0];
        float4 hv0 = u42f4(h1b[(size_t)s0 * 64 + lane]);
        float e0 = __expf(lrelu02(sel4(scs0, head) + scd_h));
        den += e0;
        acc.x = fmaf(hv0.x, e0, acc.x);
        acc.y = fmaf(hv0.y, e0, acc.y);
        acc.z = fmaf(hv0.z, e0, acc.z);
        acc.w = fmaf(hv0.w, e0, acc.w);
    }
    float inv = 1.f / (den + 1e-16f);
    float4 bb = b1[lane], gg = g1[lane], be = bb1[lane];
    ushort4 o;
    o.x = f2b(lrelu01(acc.x * inv + bb.x) * (gg.x * BN_RS) + be.x);
    o.y = f2b(lrelu01(acc.y * inv + bb.y) * (gg.y * BN_RS) + be.y);
    o.z = f2b(lrelu01(acc.z * inv + bb.z) * (gg.z * BN_RS) + be.z);
    o.w = f2b(lrelu01(acc.w * inv + bb.w) * (gg.w * BN_RS) + be.w);
    x1b[(size_t)n * 64 + lane] = o;
}

// ---------------- GAT2 aggregate: 2 half-wave groups x 4-unroll (R10-proven, LDS-free) ----
__global__ __launch_bounds__(256) void agg2_k(const int* __restrict__ row_ptr,
                                              const int* __restrict__ csr_src,
                                              const ushort4* __restrict__ h2b,  // [N*32]
                                              const float* __restrict__ sc_s,   // [N]
                                              const float* __restrict__ sc_d,
                                              const float4* __restrict__ b2,    // [32]
                                              const float4* __restrict__ g2,
                                              const float4* __restrict__ bb2,
                                              ushort4* __restrict__ x2b) {
    int n = __builtin_amdgcn_readfirstlane((blockIdx.x * 256 + threadIdx.x) >> 6);
    int lane = threadIdx.x & 63;
    if (n >= NN) return;
    int g = lane >> 5, sl = lane & 31;
    int row = row_ptr[n], end = row_ptr[n + 1];
    float scd = sc_d[n];
    float4 acc = {0.f, 0.f, 0.f, 0.f};
    float den = 0.f;
    int c = row + g;
    for (; c + 6 < end; c += 8) {
        int s0 = csr_src[c], s1 = csr_src[c + 2], s2 = csr_src[c + 4], s3 = csr_src[c + 6];
        float c0 = sc_s[s0], c1 = sc_s[s1], c2 = sc_s[s2], c3 = sc_s[s3];
        ushort4 u0 = h2b[(size_t)s0 * 32 + sl];
        ushort4 u1 = h2b[(size_t)s1 * 32 + sl];
        ushort4 u2 = h2b[(size_t)s2 * 32 + sl];
        ushort4 u3 = h2b[(size_t)s3 * 32 + sl];
        float e0 = __expf(lrelu02(c0 + scd));
        float e1 = __expf(lrelu02(c1 + scd));
        float e2 = __expf(lrelu02(c2 + scd));
        float e3 = __expf(lrelu02(c3 + scd));
        den += (e0 + e1) + (e2 + e3);
        float4 h0 = u42f4(u0), h1 = u42f4(u1), h2 = u42f4(u2), h3 = u42f4(u3);
        acc.x = fmaf(h0.x, e0, fmaf(h1.x, e1, fmaf(h2.x, e2, fmaf(h3.x, e3, acc.x))));
        acc.y = fmaf(h0.y, e0, fmaf(h1.y, e1, fmaf(h2.y, e2, fmaf(h3.y, e3, acc.y))));
        acc.z = fmaf(h0.z, e0, fmaf(h1.z, e1, fmaf(h2.z, e2, fmaf(h3.z, e3, acc.z))));
        acc.w = fmaf(h0.w, e0, fmaf(h1.w, e1, fmaf(h2.w, e2, fmaf(h3.w, e3, acc.w))));
    }
    for (; c < end; c += 2) {
        int s0 = csr_src[c];
        float e0 = __expf(lrelu02(sc_s[s0] + scd));
        float4 hv0 = u42f4(h2b[(size_t)s0 * 32 + sl]);
        den += e0;
        acc.x = fmaf(hv0.x, e0, acc.x);
        acc.y = fmaf(hv0.y, e0, acc.y);
        acc.z = fmaf(hv0.z, e0, acc.z);
        acc.w = fmaf(hv0.w, e0, acc.w);
    }
    den += __shfl_xor(den, 32);
    acc.x += __shfl_xor(acc.x, 32);
    acc.y += __shfl_xor(acc.y, 32);
    acc.z += __shfl_xor(acc.z, 32);
    acc.w += __shfl_xor(acc.w, 32);
    if (g == 0) {
        float inv = 1.f / (den + 1e-16f);
        float4 bb = b2[sl], gg = g2[sl], be = bb2[sl];
        ushort4 o;
        o.x = f2b(lrelu01(acc.x * inv + bb.x) * (gg.x * BN_RS) + be.x);
        o.y = f2b(lrelu01(acc.y * inv + bb.y) * (gg.y * BN_RS) + be.y);
        o.z = f2b(lrelu01(acc.z * inv + bb.z) * (gg.z * BN_RS) + be.z);
        o.w = f2b(lrelu01(acc.w * inv + bb.w) * (gg.w * BN_RS) + be.w);
        x2b[(size_t)n * 32 + sl] = o;
    }
}

// ---------------- GCN aggregate: 4 groups x 16 lanes x 4-unroll (R10-proven, LDS-free) ----
__global__ __launch_bounds__(256) void gcn_k(const int* __restrict__ row_ptr,
                                             const int* __restrict__ csr_src,
                                             const ushort4* __restrict__ hgb,  // [N*16]
                                             const float* __restrict__ dis,
                                             const float4* __restrict__ bg,    // [16]
                                             float4* __restrict__ x3) {        // [N*16]
    int n = __builtin_amdgcn_readfirstlane((blockIdx.x * 256 + threadIdx.x) >> 6);
    int lane = threadIdx.x & 63;
    if (n >= NN) return;
    int g = lane >> 4, sl = lane & 15;
    int row = row_ptr[n], end = row_ptr[n + 1];
    float dn = dis[n];
    float4 acc = {0.f, 0.f, 0.f, 0.f};
    int c = row + g;
    for (; c + 12 < end; c += 16) {
        int s0 = csr_src[c], s1 = csr_src[c + 4], s2 = csr_src[c + 8], s3 = csr_src[c + 12];
        float w0 = dis[s0], w1 = dis[s1], w2 = dis[s2], w3 = dis[s3];
        ushort4 u0 = hgb[(size_t)s0 * 16 + sl];
        ushort4 u1 = hgb[(size_t)s1 * 16 + sl];
        ushort4 u2 = hgb[(size_t)s2 * 16 + sl];
        ushort4 u3 = hgb[(size_t)s3 * 16 + sl];
        float4 h0 = u42f4(u0), h1 = u42f4(u1), h2 = u42f4(u2), h3 = u42f4(u3);
        acc.x = fmaf(h0.x, w0, fmaf(h1.x, w1, fmaf(h2.x, w2, fmaf(h3.x, w3, acc.x))));
        acc.y = fmaf(h0.y, w0, fmaf(h1.y, w1, fmaf(h2.y, w2, fmaf(h3.y, w3, acc.y))));
        acc.z = fmaf(h0.z, w0, fmaf(h1.z, w1, fmaf(h2.z, w2, fmaf(h3.z, w3, acc.z))));
        acc.w = fmaf(h0.w, w0, fmaf(h1.w, w1, fmaf(h2.w, w2, fmaf(h3.w, w3, acc.w))));
    }
    for (; c < end; c += 4) {
        int s0 = csr_src[c];
        float w0 = dis[s0];
        float4 hv0 = u42f4(hgb[(size_t)s0 * 16 + sl]);
        acc.x = fmaf(hv0.x, w0, acc.x);
        acc.y = fmaf(hv0.y, w0, acc.y);
        acc.z = fmaf(hv0.z, w0, acc.z);
        acc.w = fmaf(hv0.w, w0, acc.w);
    }
#pragma unroll
    for (int off = 16; off <= 32; off <<= 1) {
        acc.x += __shfl_xor(acc.x, off);
        acc.y += __shfl_xor(acc.y, off);
        acc.z += __shfl_xor(acc.z, off);
        acc.w += __shfl_xor(acc.w, off);
    }
    if (g == 0) {
        float4 bb = bg[sl];
        float4 o;
        o.x = lrelu01(acc.x * dn + bb.x);
        o.y = lrelu01(acc.y * dn + bb.y);
        o.z = lrelu01(acc.z * dn + bb.z);
        o.w = lrelu01(acc.w * dn + bb.w);
        x3[(size_t)n * 16 + sl] = o;
    }
}

// ---------------- fused mean-pool + MLP head: block per graph ----------------
__global__ __launch_bounds__(256) void poolmlp_k(const float* __restrict__ x3,
                                                 const int* __restrict__ gstart,
                                                 const float* __restrict__ l1W,
                                                 const float* __restrict__ l1b,
                                                 const float* __restrict__ g3,
                                                 const float* __restrict__ b3,
                                                 const float* __restrict__ l2W,
                                                 const float* __restrict__ l2b,
                                                 void* __restrict__ outp,
                                                 const int* __restrict__ flag) {
    __shared__ float red[4][64];
    __shared__ float pl[64];
    __shared__ float y1s[128];
    int g = blockIdx.x, t = threadIdx.x;
    int c = t & 63, r = t >> 6;
    int s = gstart[g], e = gstart[g + 1];
    float sum = 0.f;
    for (int n = s + r; n < e; n += 4) sum += x3[(size_t)n * 64 + c];
    red[r][c] = sum;
    __syncthreads();
    if (t < 64) {
        float v = red[0][t] + red[1][t] + red[2][t] + red[3][t];
        int cnt = e - s; if (cnt < 1) cnt = 1;
        pl[t] = v / (float)cnt;
    }
    __syncthreads();
    if (t < 128) {
        float acc = l1b[t];
#pragma unroll 8
        for (int j = 0; j < 64; ++j) acc = fmaf(pl[j], l1W[j * 128 + t], acc);
        acc = acc * (g3[t] * BN_RS) + b3[t];
        y1s[t] = lrelu01(acc);
    }
    __syncthreads();
    if (t < 10) {
        float o = l2b[t];
#pragma unroll 8
        for (int j = 0; j < 128; ++j) o = fmaf(y1s[j], l2W[j * 10 + t], o);
        if (*flag) ((__hip_bfloat16*)outp)[g * 10 + t] = __float2bfloat16(o);
        else       ((float*)outp)[g * 10 + t] = o;
    }
}

// weight segment sizes (W1,as1,ad1,b1,W2,as2,ad2,b2,Wg,bg,bn1g,bn1b,bn2g,bn2b,bn3g,bn3b,l1W,l1b,l2W,l2b)
static const int kSegN[NSEG]  = {32768, 256, 256, 256, 32768, 128, 128, 128, 8192, 64,
                                 256, 256, 128, 128, 128, 128, 8192, 128, 1280, 10};
static const int kSegIn[NSEG] = {3, 4, 5, 6, 7, 8, 9, 10, 11, 12, 13, 14, 15, 16, 17, 18, 19, 20, 21, 22};

extern "C" void kernel_launch(void* const* d_in, const int* in_sizes, int n_in,
                              void* d_out, int out_size, void* d_ws, size_t ws_size,
                              hipStream_t stream) {
    const void* x_raw = d_in[0];
    const int*  ei    = (const int*)d_in[1];
    const int*  batch = (const int*)d_in[2];

    // ---- workspace layout ----
    int*   flag = (int*)d_ws;
    float* ws   = (float*)d_ws;
    unsigned short* xb = (unsigned short*)(ws + 16);          // N*128 bf16
    float* wf   = ws + 16 + (size_t)NN * 64;                  // 85584 fp32 canonical
    unsigned short* W1t = (unsigned short*)(wf + 85584);      // 32768 bf16 [256][128]
    unsigned short* W2t = W1t + 32768;                        // 32768 bf16 [128][256]
    unsigned short* Wgt = W2t + 32768;                        // 8192  bf16 [64][128]
    unsigned short* h1b = Wgt + 8192;                         // N*256 bf16 (reused as h2b)
    unsigned short* x1b = h1b + (size_t)NN * 256;             // N*256 bf16
    unsigned short* x2b = x1b + (size_t)NN * 256;             // N*128 bf16
    unsigned short* hgb = x2b + (size_t)NN * 128;             // N*64 bf16
    float* x3   = (float*)(hgb + (size_t)NN * 64);            // N*64 fp32
    float* sc_s1 = x3 + (size_t)NN * 64;                      // N*4
    float* sc_d1 = sc_s1 + (size_t)NN * 4;                    // N*4
    float* sc_s2 = sc_d1 + (size_t)NN * 4;                    // N
    float* sc_d2 = sc_s2 + NN;                                // N
    float* disb  = sc_d2 + NN;                                // N
    int*   gstart = (int*)(disb + NN);                        // B+1
    int*   degi   = gstart + NB + 4;                          // N
    int*   incl   = degi + NN;                                // N
    int*   bsum   = incl + NN;                                // 256
    int*   row_ptr = bsum + 256;                              // N+1
    int*   cursor  = row_ptr + NN + 1;                        // N
    int*   csr_src = cursor + NN;                             // NE2

    int off[NSEG]; int o = 0;
    for (int s = 0; s < NSEG; ++s) { off[s] = o; o += kSegN[s]; }
    float* as1f = wf + off[1];  float* ad1f = wf + off[2];
    float* b1f  = wf + off[3];  float* as2f = wf + off[5];
    float* ad2f = wf + off[6];  float* b2f  = wf + off[7];
    float* bgf  = wf + off[9];  float* bn1g = wf + off[10]; float* bn1b = wf + off[11];
    float* bn2g = wf + off[12]; float* bn2b = wf + off[13]; float* bn3g = wf + off[14];
    float* bn3b = wf + off[15]; float* l1Wf = wf + off[16]; float* l1bf = wf + off[17];
    float* l2Wf = wf + off[18]; float* l2bf = wf + off[19];

    unsigned short* h2b = h1b;   // h1b dead after agg1_k

    // ---- prep: degi zero (memset) + detect/convert/transpose/degree-count (one kernel) ----
    hipMemsetAsync(degi, 0, NN * sizeof(int), stream);
    SegArgs sa;
    for (int s = 0; s < NSEG; ++s) { sa.src[s] = d_in[kSegIn[s]]; sa.off[s] = off[s]; }
    prep_k<<<(PREP_TOT + 255) / 256, 256, 0, stream>>>(sa, x_raw, (ushort4*)xb,
                                                       d_in[3], d_in[7], d_in[11],
                                                       wf, W1t, W2t, Wgt, ei, degi, flag);

    // ---- CSR build (by destination) + graph bounds ----
    pscan_k<<<NSB, 256, 0, stream>>>(degi, incl, bsum);
    bscan_k<<<1, 256, 0, stream>>>(bsum);
    fscan_k<<<NSB, 256, 0, stream>>>(degi, incl, bsum, batch, row_ptr, cursor, disb, gstart);
    scatter_k<<<(NE2 + 255) / 256, 256, 0, stream>>>(ei, cursor, csr_src);

    // ---- GAT layer 1 (scores fused into GEMM) ----
    mgemm1_k<<<NRT, 256, 0, stream>>>((const short*)xb, (const short*)W1t, h1b,
                                      as1f, ad1f, sc_s1, sc_d1);
    agg1_k<<<12500, 256, 0, stream>>>(row_ptr, csr_src, (const ushort4*)h1b,
                                      (const float4*)sc_s1, (const float4*)sc_d1,
                                      (const float4*)b1f, (const float4*)bn1g,
                                      (const float4*)bn1b, (ushort4*)x1b);

    // ---- GAT layer 2 (scores fused into GEMM) ----
    mgemm2_k<<<(NRT * 2 + 3) / 4, 256, 0, stream>>>((const short*)x1b, (const short*)W2t, h2b,
                                                    as2f, ad2f, sc_s2, sc_d2);
    agg2_k<<<12500, 256, 0, stream>>>(row_ptr, csr_src, (const ushort4*)h2b,
                                      sc_s2, sc_d2,
                                      (const float4*)b2f, (const float4*)bn2g,
                                      (const float4*)bn2b, (ushort4*)x2b);

    // ---- GCN + fused pool/MLP ----
    mgemm3_k<<<(NRT + 3) / 4, 256, 0, stream>>>((const short*)x2b, (const short*)Wgt, hgb);
    gcn_k<<<12500, 256, 0, stream>>>(row_ptr, csr_src, (const ushort4*)hgb, disb,
                                     (const float4*)bgf, (float4*)x3);
    poolmlp_k<<<NB, 256, 0, stream>>>(x3, gstart, l1Wf, l1bf, bn3g, bn3b, l2Wf, l2bf,
                                      d_out, flag);
}